// Round 9
// baseline (170.304 us; speedup 1.0000x reference)
//
#include <hip/hip_runtime.h>
#include <cstdint>

#define HB 8
#define CM 128
#define NHEAD 8
#define NPT 8
#define DHD 16
#define HS 64
#define WS 64
#define LTOT 4096
#define NQA 192   // fused off(128) + attn(64)
#define QAP 196   // qaT LDS pitch (floats): +4 breaks 4-way bank conflict, keeps 16B align
#define NBLK 512  // 2 blocks/CU * 256 CU — co-resident by construction

typedef float floatx4 __attribute__((ext_vector_type(4)));
typedef short bf16x8 __attribute__((ext_vector_type(8)));

__device__ __forceinline__ unsigned short f2bf_rne(float x) {
  unsigned u = __float_as_uint(x);
  return (unsigned short)((u + 0x7FFFu + ((u >> 16) & 1)) >> 16);
}
__device__ __forceinline__ void split_bf(float x, unsigned short& h, unsigned short& l) {
  unsigned u = __float_as_uint(x);
  h = (unsigned short)(u >> 16);
  float r = x - __uint_as_float(u & 0xFFFF0000u);
  l = (unsigned short)(__float_as_uint(r) >> 16);
}
__device__ __forceinline__ float fast_tanh(float x) {
  float e = __expf(2.0f * x);
  return 1.0f - 2.0f / (e + 1.0f);
}

// Weight prep -> bf16 hi/lo fragment layout: element (n,k) at (k>>3)*Nn*8 + n*8 + (k&7).
// Also zeroes the grid barrier counter (runs before fused every call -> replay-safe).
__global__ __launch_bounds__(256) void prep(const float* __restrict__ Wv,
                                            const float* __restrict__ Wo,
                                            const float* __restrict__ Wa,
                                            const float* __restrict__ Ww,
                                            const float* __restrict__ bo,
                                            const float* __restrict__ ba,
                                            unsigned short* __restrict__ wf_val,
                                            unsigned short* __restrict__ wf_qa,
                                            unsigned short* __restrict__ wf_out,
                                            float* __restrict__ bias_qa,
                                            unsigned int* __restrict__ bar) {
  const int gid = blockIdx.x * 256 + threadIdx.x;  // 14336 = 32 k4 * 448 n
  if (gid == 0) *bar = 0;
  const int k4 = gid / 448;
  const int ng = gid - k4 * 448;

  const float* src;
  unsigned short* dst;
  int Nsrc, Nn, nd, n;
  if (ng < 128) {        src = Wv; dst = wf_val; Nsrc = 128; Nn = 128; n = ng;        nd = n; }
  else if (ng < 256) {   src = Wo; dst = wf_qa;  Nsrc = 128; Nn = 192; n = ng - 128;  nd = n; }
  else if (ng < 320) {   src = Wa; dst = wf_qa;  Nsrc = 64;  Nn = 192; n = ng - 256;  nd = n + 128; }
  else {                 src = Ww; dst = wf_out; Nsrc = 128; Nn = 128; n = ng - 320;  nd = n; }

  ushort4 hi, lo;
  split_bf(src[(k4 * 4 + 0) * Nsrc + n], hi.x, lo.x);
  split_bf(src[(k4 * 4 + 1) * Nsrc + n], hi.y, lo.y);
  split_bf(src[(k4 * 4 + 2) * Nsrc + n], hi.z, lo.z);
  split_bf(src[(k4 * 4 + 3) * Nsrc + n], hi.w, lo.w);
  const int off = (k4 >> 1) * Nn * 8 + nd * 8 + (k4 & 1) * 4;
  *(ushort4*)(dst + off) = hi;
  *(ushort4*)(dst + Nn * 128 + off) = lo;

  if (gid < 128) bias_qa[gid] = bo[gid];
  else if (gid < 192) bias_qa[gid] = ba[gid - 128];
}

// One fused kernel: value-GEMM -> (qa-GEMM in LDS) -> grid barrier -> gather -> out-GEMM.
// Block = one (b, 64-l tile); b = blockIdx.x & 7 (XCD affinity: value slice stays in
// the producing XCD's L2). 512 thr, 64 KB LDS -> exactly 2 blocks/CU, all co-resident.
__global__ __launch_bounds__(512, 4) void fused(const float* __restrict__ nbr,
                                                const float* __restrict__ ext,
                                                const unsigned short* __restrict__ wf_val,
                                                const unsigned short* __restrict__ wf_qa,
                                                const unsigned short* __restrict__ wf_out,
                                                const float* __restrict__ b_val,
                                                const float* __restrict__ bias_qa,
                                                const float* __restrict__ b_out,
                                                unsigned short* __restrict__ value,
                                                float* __restrict__ out,
                                                unsigned int* __restrict__ bar) {
  __shared__ char smem[65536];
  unsigned short* AB = (unsigned short*)smem;            // staging: hi 16K, lo at +8192 us
  float* qaT = (float*)smem;                             // [64][QAP] = 50176 B
  float2* WXY = (float2*)smem;                           // [8][512] = 32768 B
  float* WA = (float*)(smem + 32768);                    // [8][512] = 16384 B
  unsigned short* FR = (unsigned short*)(smem + 49152);  // bf16 A-frag, 16384 B
  float* LF = (float*)smem;                              // [128][65] = 33280 B

  const int t = threadIdx.x;
  const int b = blockIdx.x & 7;
  const int ml0 = (blockIdx.x >> 3) * 64;
  const int wv = t >> 6, lane = t & 63;
  const int nl = lane & 15, q = lane >> 4;

  // ---- stage nbr tile (fp32 -> bf16 hi/lo, swizzled) ----
  {
    const float* src = nbr + (size_t)b * CM * LTOT + ml0;
    const int x = t & 63, kq = t >> 6;
#pragma unroll
    for (int i = 0; i < 4; i++) {
      const int kb = i * 32 + kq * 4;
      ushort4 hi, lo;
      split_bf(src[(size_t)(kb + 0) * LTOT + x], hi.x, lo.x);
      split_bf(src[(size_t)(kb + 1) * LTOT + x], hi.y, lo.y);
      split_bf(src[(size_t)(kb + 2) * LTOT + x], hi.z, lo.z);
      split_bf(src[(size_t)(kb + 3) * LTOT + x], hi.w, lo.w);
      const int off = x * 128 + (((kb >> 3) ^ (x & 15)) << 3) + (kb & 7);
      *(ushort4*)(AB + off) = hi;
      *(ushort4*)(AB + 8192 + off) = lo;
    }
  }
  __syncthreads();

  // ---- value GEMM: 8 waves, wave = 64m x 16n ----
  {
    const int wn = wv * 16;
    floatx4 acc[4];
#pragma unroll
    for (int mt = 0; mt < 4; mt++) acc[mt] = {0.0f, 0.0f, 0.0f, 0.0f};
#pragma unroll
    for (int K0 = 0; K0 < 4; K0++) {
      bf16x8 ah[4], al[4];
#pragma unroll
      for (int mt = 0; mt < 4; mt++) {
        const int off = (mt * 16 + nl) * 128 + (((K0 * 4 + q) ^ nl) << 3);
        ah[mt] = *(bf16x8*)(AB + off);
        al[mt] = *(bf16x8*)(AB + 8192 + off);
      }
      const size_t o = (size_t)(K0 * 4 + q) * CM * 8 + (wn + nl) * 8;
      const bf16x8 wh = *(const bf16x8*)(wf_val + o);
      const bf16x8 wl = *(const bf16x8*)(wf_val + (size_t)CM * 128 + o);
#pragma unroll
      for (int mt = 0; mt < 4; mt++) {
        acc[mt] = __builtin_amdgcn_mfma_f32_16x16x32_bf16(al[mt], wh, acc[mt], 0, 0, 0);
        acc[mt] = __builtin_amdgcn_mfma_f32_16x16x32_bf16(ah[mt], wl, acc[mt], 0, 0, 0);
        acc[mt] = __builtin_amdgcn_mfma_f32_16x16x32_bf16(ah[mt], wh, acc[mt], 0, 0, 0);
      }
    }
    // store value bf16: head = wv, col = nl (C/D: col=lane&15, row=q*4+r)
    const float bv = b_val[wn + nl];
    unsigned short* vp = value + ((size_t)(b * NHEAD + wv) * LTOT) * DHD + nl;
#pragma unroll
    for (int mt = 0; mt < 4; mt++)
#pragma unroll
      for (int r = 0; r < 4; r++) {
        const int m = ml0 + mt * 16 + q * 4 + r;
        vp[(size_t)m * DHD] = f2bf_rne(acc[mt][r] + bv);
      }
  }
  __syncthreads();  // drains value stores (vmcnt(0) before barrier)

  // ---- barrier ARRIVE (value visible device-wide) ----
  if (t == 0) {
    __threadfence();
    __hip_atomic_fetch_add(bar, 1u, __ATOMIC_RELEASE, __HIP_MEMORY_SCOPE_AGENT);
  }

  // ---- stage ext tile ----
  {
    const float* src = ext + (size_t)b * CM * LTOT + ml0;
    const int x = t & 63, kq = t >> 6;
#pragma unroll
    for (int i = 0; i < 4; i++) {
      const int kb = i * 32 + kq * 4;
      ushort4 hi, lo;
      split_bf(src[(size_t)(kb + 0) * LTOT + x], hi.x, lo.x);
      split_bf(src[(size_t)(kb + 1) * LTOT + x], hi.y, lo.y);
      split_bf(src[(size_t)(kb + 2) * LTOT + x], hi.z, lo.z);
      split_bf(src[(size_t)(kb + 3) * LTOT + x], hi.w, lo.w);
      const int off = x * 128 + (((kb >> 3) ^ (x & 15)) << 3) + (kb & 7);
      *(ushort4*)(AB + off) = hi;
      *(ushort4*)(AB + 8192 + off) = lo;
    }
  }
  __syncthreads();

  // ---- qa GEMM: 8 waves, wave = 32m x 48n; result -> qaT LDS (never global) ----
  {
    const int wm = (wv >> 2) * 32;
    const int wn = (wv & 3) * 48;
    floatx4 acc[2][3];
#pragma unroll
    for (int mt = 0; mt < 2; mt++)
#pragma unroll
      for (int j = 0; j < 3; j++) acc[mt][j] = {0.0f, 0.0f, 0.0f, 0.0f};
#pragma unroll
    for (int K0 = 0; K0 < 4; K0++) {
      bf16x8 ah[2], al[2];
#pragma unroll
      for (int mt = 0; mt < 2; mt++) {
        const int off = (wm + mt * 16 + nl) * 128 + (((K0 * 4 + q) ^ nl) << 3);
        ah[mt] = *(bf16x8*)(AB + off);
        al[mt] = *(bf16x8*)(AB + 8192 + off);
      }
#pragma unroll
      for (int j = 0; j < 3; j++) {
        const size_t o = (size_t)(K0 * 4 + q) * NQA * 8 + (wn + j * 16 + nl) * 8;
        const bf16x8 wh = *(const bf16x8*)(wf_qa + o);
        const bf16x8 wl = *(const bf16x8*)(wf_qa + (size_t)NQA * 128 + o);
#pragma unroll
        for (int mt = 0; mt < 2; mt++) {
          acc[mt][j] = __builtin_amdgcn_mfma_f32_16x16x32_bf16(al[mt], wh, acc[mt][j], 0, 0, 0);
          acc[mt][j] = __builtin_amdgcn_mfma_f32_16x16x32_bf16(ah[mt], wl, acc[mt][j], 0, 0, 0);
          acc[mt][j] = __builtin_amdgcn_mfma_f32_16x16x32_bf16(ah[mt], wh, acc[mt][j], 0, 0, 0);
        }
      }
    }
    __syncthreads();  // done reading AB; qaT overwrites it
#pragma unroll
    for (int j = 0; j < 3; j++) {
      const int n = wn + j * 16 + nl;
      const float bv = bias_qa[n];
#pragma unroll
      for (int mt = 0; mt < 2; mt++)
#pragma unroll
        for (int r = 0; r < 4; r++)
          qaT[(wm + mt * 16 + q * 4 + r) * QAP + n] = acc[mt][j][r] + bv;
    }
  }
  __syncthreads();

  // ---- phase 0: per-(l,h) sampling params from qaT ----
  {
    const int ll = t >> 3, h = t & 7;
    const float* qrow = qaT + ll * QAP;
    float4 of[4];
#pragma unroll
    for (int j = 0; j < 4; j++) of[j] = *(const float4*)(qrow + h * 16 + j * 4);
    const float4 lga = *(const float4*)(qrow + 128 + h * 8);
    const float4 lgb = *(const float4*)(qrow + 128 + h * 8 + 4);
    __syncthreads();  // all qaT reads done before WXY/WA overwrite
    const float lg[8] = {lga.x, lga.y, lga.z, lga.w, lgb.x, lgb.y, lgb.z, lgb.w};
    float m = lg[0];
#pragma unroll
    for (int p = 1; p < 8; p++) m = fmaxf(m, lg[p]);
    float e[8], s = 0.0f;
#pragma unroll
    for (int p = 0; p < 8; p++) { e[p] = __expf(lg[p] - m); s += e[p]; }
    const float inv = 1.0f / s;
    const int l = ml0 + ll;
    const float xf = (float)(l & (WS - 1));
    const float yf = (float)(l >> 6);
#pragma unroll
    for (int p = 0; p < 8; p++) {
      const float ox = (p & 1) ? of[p >> 1].z : of[p >> 1].x;
      const float oy = (p & 1) ? of[p >> 1].w : of[p >> 1].y;
      WXY[p * 512 + t] = {xf + 10.0f * fast_tanh(ox), yf + 10.0f * fast_tanh(oy)};
      WA[p * 512 + t] = e[p] * inv;
    }
  }

  // ---- barrier WAIT (all blocks' value written) ----
  if (t == 0) {
    while (__hip_atomic_load(bar, __ATOMIC_ACQUIRE, __HIP_MEMORY_SCOPE_AGENT) < NBLK)
      __builtin_amdgcn_s_sleep(2);
    __threadfence();
  }
  __syncthreads();

  // ---- gather: thread = (pair uu=(ll,h), d4); 4 passes; bf16 value, quad-coop ----
  {
    const int d4 = t & 3;
    const int u = t >> 2;
#pragma unroll
    for (int ps = 0; ps < 4; ps++) {
      const int uu = ps * 128 + u;
      const int ll = uu >> 3;
      const int h = uu & 7;
      const unsigned short* vbb = value + ((size_t)(b * NHEAD + h) * LTOT) * DHD + d4 * 4;

      float4 o = {0.0f, 0.0f, 0.0f, 0.0f};
#pragma unroll
      for (int p = 0; p < 8; p++) {
        const float2 pxy = WXY[p * 512 + uu];
        const float aw = WA[p * 512 + uu];
        const float x0f = floorf(pxy.x), y0f = floorf(pxy.y);
        const float fx = pxy.x - x0f, fy = pxy.y - y0f;
        const int ix = (int)x0f, iy = (int)y0f;
#pragma unroll
        for (int c = 0; c < 4; c++) {
          const int cdx = c & 1, cdy = c >> 1;
          const int jx = ix + cdx, jy = iy + cdy;
          const float wx = cdx ? fx : 1.0f - fx;
          const float wy = cdy ? fy : 1.0f - fy;
          const bool valid = ((unsigned)jx < WS) & ((unsigned)jy < HS);
          const float wc = valid ? aw * wx * wy : 0.0f;
          const int cx = min(max(jx, 0), WS - 1);
          const int cy = min(max(jy, 0), HS - 1);
          const uint2 rw = *(const uint2*)(vbb + (size_t)((cy << 6) + cx) * DHD);
          o.x += wc * __uint_as_float(rw.x << 16);
          o.y += wc * __uint_as_float(rw.x & 0xFFFF0000u);
          o.z += wc * __uint_as_float(rw.y << 16);
          o.w += wc * __uint_as_float(rw.y & 0xFFFF0000u);
        }
      }
      const int off = ll * 128 + (((h * 2 + (d4 >> 1)) ^ (ll & 15)) << 3) + (d4 & 1) * 4;
      ushort4 st = {f2bf_rne(o.x), f2bf_rne(o.y), f2bf_rne(o.z), f2bf_rne(o.w)};
      *(ushort4*)(FR + off) = st;
    }
  }
  __syncthreads();

  // ---- out GEMM: 8 waves, wave = 16m x 64n ----
  {
    const int wm = (wv >> 1) * 16;
    const int wn = (wv & 1) * 64;
    floatx4 acc[4];
#pragma unroll
    for (int j = 0; j < 4; j++) acc[j] = {0.0f, 0.0f, 0.0f, 0.0f};
#pragma unroll
    for (int K0 = 0; K0 < 4; K0++) {
      const int m = wm + nl;
      const int off = m * 128 + (((K0 * 4 + q) ^ (m & 15)) << 3);
      const bf16x8 ah = *(bf16x8*)(FR + off);
#pragma unroll
      for (int j = 0; j < 4; j++) {
        const int n = wn + j * 16 + nl;
        const size_t o = (size_t)(K0 * 4 + q) * CM * 8 + n * 8;
        const bf16x8 wh = *(const bf16x8*)(wf_out + o);
        const bf16x8 wl = *(const bf16x8*)(wf_out + (size_t)CM * 128 + o);
        acc[j] = __builtin_amdgcn_mfma_f32_16x16x32_bf16(ah, wl, acc[j], 0, 0, 0);
        acc[j] = __builtin_amdgcn_mfma_f32_16x16x32_bf16(ah, wh, acc[j], 0, 0, 0);
      }
    }
    __syncthreads();  // WXY/WA dead; FR (>=49152) untouched by LF
#pragma unroll
    for (int j = 0; j < 4; j++) {
      const int n = wn + j * 16 + nl;
#pragma unroll
      for (int r = 0; r < 4; r++) LF[n * 65 + wm + q * 4 + r] = acc[j][r];
    }
    __syncthreads();
#pragma unroll
    for (int i = 0; i < 16; i++) {
      const int idx = t + i * 512;
      const int n = idx >> 6, m = idx & 63;
      out[((size_t)b * CM + n) * LTOT + ml0 + m] = LF[n * 65 + m] + b_out[n];
    }
  }
}

extern "C" void kernel_launch(void* const* d_in, const int* in_sizes, int n_in,
                              void* d_out, int out_size, void* d_ws, size_t ws_size,
                              hipStream_t stream) {
  const float* nbr    = (const float*)d_in[0];
  const float* ext    = (const float*)d_in[1];
  const float* W_val  = (const float*)d_in[2];
  const float* b_val  = (const float*)d_in[3];
  const float* W_off  = (const float*)d_in[4];
  const float* b_off  = (const float*)d_in[5];
  const float* W_attn = (const float*)d_in[6];
  const float* b_attn = (const float*)d_in[7];
  const float* W_out  = (const float*)d_in[8];
  const float* b_out  = (const float*)d_in[9];
  float* out = (float*)d_out;

  unsigned short* value = (unsigned short*)d_ws;             // 8.39 MB bf16 [b][h][l][16]
  unsigned short* wf_val = value + (size_t)HB * NHEAD * LTOT * DHD;  // 64 KB
  unsigned short* wf_qa  = wf_val + 128 * 128 * 2;           // 96 KB
  unsigned short* wf_out = wf_qa + 192 * 128 * 2;            // 64 KB
  float* bias_qa = (float*)(wf_out + 128 * 128 * 2);         // 768 B
  unsigned int* bar = (unsigned int*)(bias_qa + 256);        // grid barrier counter

  prep<<<56, 256, 0, stream>>>(W_val, W_off, W_attn, W_out, b_off, b_attn,
                               wf_val, wf_qa, wf_out, bias_qa, bar);
  fused<<<dim3(NBLK), 512, 0, stream>>>(nbr, ext, wf_val, wf_qa, wf_out,
                                        b_val, bias_qa, b_out, value, out, bar);
}

// Round 11
// 142.073 us; speedup vs baseline: 1.1987x; 1.1987x over previous
//
#include <hip/hip_runtime.h>
#include <cstdint>

#define HB 8
#define CM 128
#define NHEAD 8
#define NPT 8
#define DHD 16
#define HS 64
#define WS 64
#define LTOT 4096
#define NQA 192   // fused off(128) + attn(64)
#define QAP 196   // qaT LDS pitch (floats)

typedef float floatx4 __attribute__((ext_vector_type(4)));
typedef short bf16x8 __attribute__((ext_vector_type(8)));

__device__ __forceinline__ unsigned short f2bf_rne(float x) {
  unsigned u = __float_as_uint(x);
  return (unsigned short)((u + 0x7FFFu + ((u >> 16) & 1)) >> 16);
}
__device__ __forceinline__ void split_bf(float x, unsigned short& h, unsigned short& l) {
  unsigned u = __float_as_uint(x);
  h = (unsigned short)(u >> 16);
  float r = x - __uint_as_float(u & 0xFFFF0000u);
  l = (unsigned short)(__float_as_uint(r) >> 16);
}
__device__ __forceinline__ float fast_tanh(float x) {
  float e = __expf(2.0f * x);
  return 1.0f - 2.0f / (e + 1.0f);
}

// Weight prep -> bf16 hi/lo fragment layout: element (n,k) at (k>>3)*Nn*8 + n*8 + (k&7).
__global__ __launch_bounds__(256) void prep(const float* __restrict__ Wv,
                                            const float* __restrict__ Wo,
                                            const float* __restrict__ Wa,
                                            const float* __restrict__ Ww,
                                            const float* __restrict__ bo,
                                            const float* __restrict__ ba,
                                            unsigned short* __restrict__ wf_val,
                                            unsigned short* __restrict__ wf_qa,
                                            unsigned short* __restrict__ wf_out,
                                            float* __restrict__ bias_qa) {
  const int gid = blockIdx.x * 256 + threadIdx.x;  // 14336 = 32 k4 * 448 n
  const int k4 = gid / 448;
  const int ng = gid - k4 * 448;

  const float* src;
  unsigned short* dst;
  int Nsrc, Nn, nd, n;
  if (ng < 128) {        src = Wv; dst = wf_val; Nsrc = 128; Nn = 128; n = ng;        nd = n; }
  else if (ng < 256) {   src = Wo; dst = wf_qa;  Nsrc = 128; Nn = 192; n = ng - 128;  nd = n; }
  else if (ng < 320) {   src = Wa; dst = wf_qa;  Nsrc = 64;  Nn = 192; n = ng - 256;  nd = n + 128; }
  else {                 src = Ww; dst = wf_out; Nsrc = 128; Nn = 128; n = ng - 320;  nd = n; }

  ushort4 hi, lo;
  split_bf(src[(k4 * 4 + 0) * Nsrc + n], hi.x, lo.x);
  split_bf(src[(k4 * 4 + 1) * Nsrc + n], hi.y, lo.y);
  split_bf(src[(k4 * 4 + 2) * Nsrc + n], hi.z, lo.z);
  split_bf(src[(k4 * 4 + 3) * Nsrc + n], hi.w, lo.w);
  const int off = (k4 >> 1) * Nn * 8 + nd * 8 + (k4 & 1) * 4;
  *(ushort4*)(dst + off) = hi;
  *(ushort4*)(dst + Nn * 128 + off) = lo;

  if (gid < 128) bias_qa[gid] = bo[gid];
  else if (gid < 192) bias_qa[gid] = ba[gid - 128];
}

// K1: value projection. Tile 64 m x 128 n, 256 thr (4 waves, wave = 32m x 64n).
// 3-term bf16 split. Stores value bf16 [b][h][l][16].
__global__ __launch_bounds__(256, 4) void gemm_val(const float* __restrict__ nbr,
                                                   const unsigned short* __restrict__ WF,
                                                   const float* __restrict__ bias,
                                                   unsigned short* __restrict__ value) {
  __shared__ char smem[32768];
  unsigned short* AB = (unsigned short*)smem;  // hi [64][128]; lo at +8192 us
  const int t = threadIdx.x;
  const int ml0 = blockIdx.x * 64;
  const int b = blockIdx.y;

  {
    const float* src = nbr + (size_t)b * CM * LTOT + ml0;
    const int x = t & 63, kq = t >> 6;
#pragma unroll
    for (int i = 0; i < 8; i++) {
      const int kb = kq * 4 + i * 16;
      ushort4 hi, lo;
      split_bf(src[(size_t)(kb + 0) * LTOT + x], hi.x, lo.x);
      split_bf(src[(size_t)(kb + 1) * LTOT + x], hi.y, lo.y);
      split_bf(src[(size_t)(kb + 2) * LTOT + x], hi.z, lo.z);
      split_bf(src[(size_t)(kb + 3) * LTOT + x], hi.w, lo.w);
      const int off = x * 128 + (((kb >> 3) ^ (x & 15)) << 3) + (kb & 7);
      *(ushort4*)(AB + off) = hi;
      *(ushort4*)(AB + 8192 + off) = lo;
    }
  }
  __syncthreads();

  const int w = t >> 6, lane = t & 63;
  const int wm = (w >> 1) * 32, wn = (w & 1) * 64;
  const int nl = lane & 15, q = lane >> 4;

  floatx4 acc[2][4];
#pragma unroll
  for (int mt = 0; mt < 2; mt++)
#pragma unroll
    for (int j = 0; j < 4; j++) acc[mt][j] = {0.0f, 0.0f, 0.0f, 0.0f};

#pragma unroll
  for (int K0 = 0; K0 < 4; K0++) {
    bf16x8 ah[2], al[2];
#pragma unroll
    for (int mt = 0; mt < 2; mt++) {
      const int m = wm + mt * 16 + nl;
      const int off = m * 128 + (((K0 * 4 + q) ^ (m & 15)) << 3);
      ah[mt] = *(bf16x8*)(AB + off);
      al[mt] = *(bf16x8*)(AB + 8192 + off);
    }
#pragma unroll
    for (int j = 0; j < 4; j++) {
      const size_t o = (size_t)(K0 * 4 + q) * CM * 8 + (wn + j * 16 + nl) * 8;
      const bf16x8 wh = *(const bf16x8*)(WF + o);
      const bf16x8 wl = *(const bf16x8*)(WF + (size_t)CM * 128 + o);
#pragma unroll
      for (int mt = 0; mt < 2; mt++) {
        acc[mt][j] = __builtin_amdgcn_mfma_f32_16x16x32_bf16(al[mt], wh, acc[mt][j], 0, 0, 0);
        acc[mt][j] = __builtin_amdgcn_mfma_f32_16x16x32_bf16(ah[mt], wl, acc[mt][j], 0, 0, 0);
        acc[mt][j] = __builtin_amdgcn_mfma_f32_16x16x32_bf16(ah[mt], wh, acc[mt][j], 0, 0, 0);
      }
    }
  }

  // C/D: col=lane&15 -> n (channel), row=q*4+r -> m (l). value[b][h][l][16] bf16.
#pragma unroll
  for (int j = 0; j < 4; j++) {
    const int gc = wn + j * 16 + nl;
    const float bv = bias[gc];
    unsigned short* vp = value + ((size_t)(b * NHEAD + (gc >> 4)) * LTOT) * DHD + (gc & 15);
#pragma unroll
    for (int mt = 0; mt < 2; mt++)
#pragma unroll
      for (int r = 0; r < 4; r++) {
        const int m = ml0 + wm + mt * 16 + q * 4 + r;
        vp[(size_t)m * DHD] = f2bf_rne(acc[mt][j][r] + bv);
      }
  }
}

// K2: per 32-l tile: stage ext -> qa GEMM (to LDS only) -> sampling params ->
// quad-coop gather from bf16 value (XCD-affine b) -> out GEMM, direct f4 stores.
// 256 thr, 41.5 KB LDS -> 3 blocks/CU; 1024 independent blocks.
__global__ __launch_bounds__(256, 3) void samp(const float* __restrict__ ext,
                                               const unsigned short* __restrict__ value,
                                               const unsigned short* __restrict__ wf_qa,
                                               const unsigned short* __restrict__ wf_out,
                                               const float* __restrict__ bias_qa,
                                               const float* __restrict__ b_out,
                                               float* __restrict__ out) {
  __shared__ char smem[41472];
  unsigned short* AB = (unsigned short*)smem;            // [32][128] hi; lo at +4096 us
  float* qaT = (float*)(smem + 16384);                   // [32][QAP] = 25088 B
  float2* WXY = (float2*)smem;                           // [8][256] = 16384 B
  float* WA = (float*)(smem + 16384);                    // [8][256] = 8192 B
  unsigned short* FR = (unsigned short*)(smem + 24576);  // [32][128] bf16 = 8192 B

  const int t = threadIdx.x;
  const int b = blockIdx.x & 7;                          // XCD affinity
  const int ml0 = (blockIdx.x >> 3) * 32;
  const int w = t >> 6, lane = t & 63;
  const int nl = lane & 15, q = lane >> 4;

  // ---- stage ext 32-l tile (fp32 -> bf16 hi/lo, swizzled) ----
  {
    const float* src = ext + (size_t)b * CM * LTOT + ml0;
    const int x = t & 31, kq = t >> 5;  // kq 0..7
#pragma unroll
    for (int i = 0; i < 4; i++) {
      const int kb = i * 32 + kq * 4;
      ushort4 hi, lo;
      split_bf(src[(size_t)(kb + 0) * LTOT + x], hi.x, lo.x);
      split_bf(src[(size_t)(kb + 1) * LTOT + x], hi.y, lo.y);
      split_bf(src[(size_t)(kb + 2) * LTOT + x], hi.z, lo.z);
      split_bf(src[(size_t)(kb + 3) * LTOT + x], hi.w, lo.w);
      const int off = x * 128 + (((kb >> 3) ^ (x & 15)) << 3) + (kb & 7);
      *(ushort4*)(AB + off) = hi;
      *(ushort4*)(AB + 4096 + off) = lo;
    }
  }
  __syncthreads();

  // ---- qa GEMM: 32m x 192n, 4 waves, wave = 16m x 96n; result -> qaT (LDS) ----
  {
    const int wm = (w & 1) * 16;
    const int wn = (w >> 1) * 96;
    floatx4 acc[6];
#pragma unroll
    for (int j = 0; j < 6; j++) acc[j] = {0.0f, 0.0f, 0.0f, 0.0f};
#pragma unroll
    for (int K0 = 0; K0 < 4; K0++) {
      const int m = wm + nl;
      const int off = m * 128 + (((K0 * 4 + q) ^ (m & 15)) << 3);
      const bf16x8 ah = *(bf16x8*)(AB + off);
      const bf16x8 al = *(bf16x8*)(AB + 4096 + off);
#pragma unroll
      for (int j = 0; j < 6; j++) {
        const size_t o = (size_t)(K0 * 4 + q) * NQA * 8 + (wn + j * 16 + nl) * 8;
        const bf16x8 wh = *(const bf16x8*)(wf_qa + o);
        const bf16x8 wl = *(const bf16x8*)(wf_qa + (size_t)NQA * 128 + o);
        acc[j] = __builtin_amdgcn_mfma_f32_16x16x32_bf16(al, wh, acc[j], 0, 0, 0);
        acc[j] = __builtin_amdgcn_mfma_f32_16x16x32_bf16(ah, wl, acc[j], 0, 0, 0);
        acc[j] = __builtin_amdgcn_mfma_f32_16x16x32_bf16(ah, wh, acc[j], 0, 0, 0);
      }
    }
#pragma unroll
    for (int j = 0; j < 6; j++) {
      const int n = wn + j * 16 + nl;
      const float bv = bias_qa[n];
#pragma unroll
      for (int r = 0; r < 4; r++)
        qaT[(wm + q * 4 + r) * QAP + n] = acc[j][r] + bv;
    }
  }
  __syncthreads();

  // ---- sampling params: thread = (ll = t>>3, h = t&7) ----
  {
    const int ll = t >> 3, h = t & 7;
    const float* qrow = qaT + ll * QAP;
    float4 of[4];
#pragma unroll
    for (int j = 0; j < 4; j++) of[j] = *(const float4*)(qrow + h * 16 + j * 4);
    const float4 lga = *(const float4*)(qrow + 128 + h * 8);
    const float4 lgb = *(const float4*)(qrow + 128 + h * 8 + 4);
    __syncthreads();  // qaT fully read -> WXY/WA may overwrite
    const float lg[8] = {lga.x, lga.y, lga.z, lga.w, lgb.x, lgb.y, lgb.z, lgb.w};
    float m = lg[0];
#pragma unroll
    for (int p = 1; p < 8; p++) m = fmaxf(m, lg[p]);
    float e[8], s = 0.0f;
#pragma unroll
    for (int p = 0; p < 8; p++) { e[p] = __expf(lg[p] - m); s += e[p]; }
    const float inv = 1.0f / s;
    const int l = ml0 + ll;
    const float xf = (float)(l & (WS - 1));
    const float yf = (float)(l >> 6);
#pragma unroll
    for (int p = 0; p < 8; p++) {
      const float ox = (p & 1) ? of[p >> 1].z : of[p >> 1].x;
      const float oy = (p & 1) ? of[p >> 1].w : of[p >> 1].y;
      WXY[p * 256 + t] = {xf + 10.0f * fast_tanh(ox), yf + 10.0f * fast_tanh(oy)};
      WA[p * 256 + t] = e[p] * inv;
    }
  }
  __syncthreads();

  // ---- gather: thread = (uu=(ll,h), d4), 4 passes; bf16 value, quad-coop ----
  {
    const int d4 = t & 3;
    const int u = t >> 2;  // 0..63
#pragma unroll
    for (int ps = 0; ps < 4; ps++) {
      const int uu = ps * 64 + u;
      const int ll = uu >> 3;
      const int h = uu & 7;
      const unsigned short* vbb = value + ((size_t)(b * NHEAD + h) * LTOT) * DHD + d4 * 4;

      float4 o = {0.0f, 0.0f, 0.0f, 0.0f};
#pragma unroll
      for (int p = 0; p < 8; p++) {
        const float2 pxy = WXY[p * 256 + uu];
        const float aw = WA[p * 256 + uu];
        const float x0f = floorf(pxy.x), y0f = floorf(pxy.y);
        const float fx = pxy.x - x0f, fy = pxy.y - y0f;
        const int ix = (int)x0f, iy = (int)y0f;
#pragma unroll
        for (int c = 0; c < 4; c++) {
          const int cdx = c & 1, cdy = c >> 1;
          const int jx = ix + cdx, jy = iy + cdy;
          const float wx = cdx ? fx : 1.0f - fx;
          const float wy = cdy ? fy : 1.0f - fy;
          const bool valid = ((unsigned)jx < WS) & ((unsigned)jy < HS);
          const float wc = valid ? aw * wx * wy : 0.0f;
          const int cx = min(max(jx, 0), WS - 1);
          const int cy = min(max(jy, 0), HS - 1);
          const uint2 rw = *(const uint2*)(vbb + (size_t)((cy << 6) + cx) * DHD);
          o.x += wc * __uint_as_float(rw.x << 16);
          o.y += wc * __uint_as_float(rw.x & 0xFFFF0000u);
          o.z += wc * __uint_as_float(rw.y << 16);
          o.w += wc * __uint_as_float(rw.y & 0xFFFF0000u);
        }
      }
      const int off = ll * 128 + (((h * 2 + (d4 >> 1)) ^ (ll & 15)) << 3) + (d4 & 1) * 4;
      ushort4 st = {f2bf_rne(o.x), f2bf_rne(o.y), f2bf_rne(o.z), f2bf_rne(o.w)};
      *(ushort4*)(FR + off) = st;
    }
  }
  __syncthreads();

  // ---- out GEMM: 32m x 128n, 4 waves, wave = 16m x 64n; direct float4 stores ----
  {
    const int wm = (w & 1) * 16;
    const int wn = (w >> 1) * 64;
    floatx4 acc[4];
#pragma unroll
    for (int j = 0; j < 4; j++) acc[j] = {0.0f, 0.0f, 0.0f, 0.0f};
#pragma unroll
    for (int K0 = 0; K0 < 4; K0++) {
      const int m = wm + nl;
      const int off = m * 128 + (((K0 * 4 + q) ^ (m & 15)) << 3);
      const bf16x8 ah = *(bf16x8*)(FR + off);
#pragma unroll
      for (int j = 0; j < 4; j++) {
        const int n = wn + j * 16 + nl;
        const size_t o = (size_t)(K0 * 4 + q) * CM * 8 + n * 8;
        const bf16x8 wh = *(const bf16x8*)(wf_out + o);
        const bf16x8 wl = *(const bf16x8*)(wf_out + (size_t)CM * 128 + o);
        acc[j] = __builtin_amdgcn_mfma_f32_16x16x32_bf16(ah, wl, acc[j], 0, 0, 0);
        acc[j] = __builtin_amdgcn_mfma_f32_16x16x32_bf16(ah, wh, acc[j], 0, 0, 0);
      }
    }
    // C/D: col=nl -> n, rows q*4+r -> m (contiguous in bchw) => float4 store
#pragma unroll
    for (int j = 0; j < 4; j++) {
      const int gc = wn + j * 16 + nl;
      const float bv = b_out[gc];
      float4 st = {acc[j][0] + bv, acc[j][1] + bv, acc[j][2] + bv, acc[j][3] + bv};
      *(float4*)(out + ((size_t)b * CM + gc) * LTOT + ml0 + wm + q * 4) = st;
    }
  }
}

extern "C" void kernel_launch(void* const* d_in, const int* in_sizes, int n_in,
                              void* d_out, int out_size, void* d_ws, size_t ws_size,
                              hipStream_t stream) {
  const float* nbr    = (const float*)d_in[0];
  const float* ext    = (const float*)d_in[1];
  const float* W_val  = (const float*)d_in[2];
  const float* b_val  = (const float*)d_in[3];
  const float* W_off  = (const float*)d_in[4];
  const float* b_off  = (const float*)d_in[5];
  const float* W_attn = (const float*)d_in[6];
  const float* b_attn = (const float*)d_in[7];
  const float* W_out  = (const float*)d_in[8];
  const float* b_out  = (const float*)d_in[9];
  float* out = (float*)d_out;

  unsigned short* value = (unsigned short*)d_ws;             // 8.39 MB bf16 [b][h][l][16]
  unsigned short* wf_val = value + (size_t)HB * NHEAD * LTOT * DHD;  // 64 KB
  unsigned short* wf_qa  = wf_val + 128 * 128 * 2;           // 96 KB
  unsigned short* wf_out = wf_qa + 192 * 128 * 2;            // 64 KB
  float* bias_qa = (float*)(wf_out + 128 * 128 * 2);         // 768 B

  prep<<<56, 256, 0, stream>>>(W_val, W_off, W_attn, W_out, b_off, b_attn,
                               wf_val, wf_qa, wf_out, bias_qa);
  gemm_val<<<dim3(64, HB), 256, 0, stream>>>(nbr, wf_val, b_val, value);
  samp<<<dim3(128 * HB), 256, 0, stream>>>(ext, value, wf_qa, wf_out, bias_qa, b_out, out);
}

// Round 12
// 135.616 us; speedup vs baseline: 1.2558x; 1.0476x over previous
//
#include <hip/hip_runtime.h>
#include <cstdint>

#define HB 8
#define CM 128
#define NHEAD 8
#define NPT 8
#define DHD 16
#define HS 64
#define WS 64
#define LTOT 4096
#define NQA 192   // fused off(128) + attn(64)
#define QAP 192   // qaT LDS pitch (floats): 192 -> total LDS 40960 B = 4 blocks/CU
#define LFP 132   // gemm_val transpose pitch (floats): 132%32=4 spreads banks

typedef float floatx4 __attribute__((ext_vector_type(4)));
typedef short bf16x8 __attribute__((ext_vector_type(8)));

__device__ __forceinline__ unsigned short f2bf_rne(float x) {
  unsigned u = __float_as_uint(x);
  return (unsigned short)((u + 0x7FFFu + ((u >> 16) & 1)) >> 16);
}
__device__ __forceinline__ void split_bf(float x, unsigned short& h, unsigned short& l) {
  unsigned u = __float_as_uint(x);
  h = (unsigned short)(u >> 16);
  float r = x - __uint_as_float(u & 0xFFFF0000u);
  l = (unsigned short)(__float_as_uint(r) >> 16);
}
__device__ __forceinline__ float fast_tanh(float x) {
  float e = __expf(2.0f * x);
  return 1.0f - 2.0f / (e + 1.0f);
}

// Weight prep -> bf16 hi/lo fragment layout: element (n,k) at (k>>3)*Nn*8 + n*8 + (k&7).
__global__ __launch_bounds__(256) void prep(const float* __restrict__ Wv,
                                            const float* __restrict__ Wo,
                                            const float* __restrict__ Wa,
                                            const float* __restrict__ Ww,
                                            const float* __restrict__ bo,
                                            const float* __restrict__ ba,
                                            unsigned short* __restrict__ wf_val,
                                            unsigned short* __restrict__ wf_qa,
                                            unsigned short* __restrict__ wf_out,
                                            float* __restrict__ bias_qa) {
  const int gid = blockIdx.x * 256 + threadIdx.x;  // 14336 = 32 k4 * 448 n
  const int k4 = gid / 448;
  const int ng = gid - k4 * 448;

  const float* src;
  unsigned short* dst;
  int Nsrc, Nn, nd, n;
  if (ng < 128) {        src = Wv; dst = wf_val; Nsrc = 128; Nn = 128; n = ng;        nd = n; }
  else if (ng < 256) {   src = Wo; dst = wf_qa;  Nsrc = 128; Nn = 192; n = ng - 128;  nd = n; }
  else if (ng < 320) {   src = Wa; dst = wf_qa;  Nsrc = 64;  Nn = 192; n = ng - 256;  nd = n + 128; }
  else {                 src = Ww; dst = wf_out; Nsrc = 128; Nn = 128; n = ng - 320;  nd = n; }

  ushort4 hi, lo;
  split_bf(src[(k4 * 4 + 0) * Nsrc + n], hi.x, lo.x);
  split_bf(src[(k4 * 4 + 1) * Nsrc + n], hi.y, lo.y);
  split_bf(src[(k4 * 4 + 2) * Nsrc + n], hi.z, lo.z);
  split_bf(src[(k4 * 4 + 3) * Nsrc + n], hi.w, lo.w);
  const int off = (k4 >> 1) * Nn * 8 + nd * 8 + (k4 & 1) * 4;
  *(ushort4*)(dst + off) = hi;
  *(ushort4*)(dst + Nn * 128 + off) = lo;

  if (gid < 128) bias_qa[gid] = bo[gid];
  else if (gid < 192) bias_qa[gid] = ba[gid - 128];
}

// K1: value projection. Tile 64 m x 128 n, 256 thr (4 waves, wave = 32m x 64n).
// 3-term bf16 split. Epilogue: LDS transpose -> COALESCED uint4 bf16 stores
// (the R11 version's 2B/32B-stride scatter stores were ~85 us of TA serialization).
__global__ __launch_bounds__(256, 4) void gemm_val(const float* __restrict__ nbr,
                                                   const unsigned short* __restrict__ WF,
                                                   const float* __restrict__ bias,
                                                   unsigned short* __restrict__ value) {
  __shared__ char smem[33792];                 // staging 32768; transpose 64*132*4=33792
  unsigned short* AB = (unsigned short*)smem;  // hi [64][128]; lo at +8192 us
  const int t = threadIdx.x;
  const int ml0 = blockIdx.x * 64;
  const int b = blockIdx.y;

  {
    const float* src = nbr + (size_t)b * CM * LTOT + ml0;
    const int x = t & 63, kq = t >> 6;
#pragma unroll
    for (int i = 0; i < 8; i++) {
      const int kb = kq * 4 + i * 16;
      ushort4 hi, lo;
      split_bf(src[(size_t)(kb + 0) * LTOT + x], hi.x, lo.x);
      split_bf(src[(size_t)(kb + 1) * LTOT + x], hi.y, lo.y);
      split_bf(src[(size_t)(kb + 2) * LTOT + x], hi.z, lo.z);
      split_bf(src[(size_t)(kb + 3) * LTOT + x], hi.w, lo.w);
      const int off = x * 128 + (((kb >> 3) ^ (x & 15)) << 3) + (kb & 7);
      *(ushort4*)(AB + off) = hi;
      *(ushort4*)(AB + 8192 + off) = lo;
    }
  }
  __syncthreads();

  const int w = t >> 6, lane = t & 63;
  const int wm = (w >> 1) * 32, wn = (w & 1) * 64;
  const int nl = lane & 15, q = lane >> 4;

  floatx4 acc[2][4];
#pragma unroll
  for (int mt = 0; mt < 2; mt++)
#pragma unroll
    for (int j = 0; j < 4; j++) acc[mt][j] = {0.0f, 0.0f, 0.0f, 0.0f};

#pragma unroll
  for (int K0 = 0; K0 < 4; K0++) {
    bf16x8 ah[2], al[2];
#pragma unroll
    for (int mt = 0; mt < 2; mt++) {
      const int m = wm + mt * 16 + nl;
      const int off = m * 128 + (((K0 * 4 + q) ^ (m & 15)) << 3);
      ah[mt] = *(bf16x8*)(AB + off);
      al[mt] = *(bf16x8*)(AB + 8192 + off);
    }
#pragma unroll
    for (int j = 0; j < 4; j++) {
      const size_t o = (size_t)(K0 * 4 + q) * CM * 8 + (wn + j * 16 + nl) * 8;
      const bf16x8 wh = *(const bf16x8*)(WF + o);
      const bf16x8 wl = *(const bf16x8*)(WF + (size_t)CM * 128 + o);
#pragma unroll
      for (int mt = 0; mt < 2; mt++) {
        acc[mt][j] = __builtin_amdgcn_mfma_f32_16x16x32_bf16(al[mt], wh, acc[mt][j], 0, 0, 0);
        acc[mt][j] = __builtin_amdgcn_mfma_f32_16x16x32_bf16(ah[mt], wl, acc[mt][j], 0, 0, 0);
        acc[mt][j] = __builtin_amdgcn_mfma_f32_16x16x32_bf16(ah[mt], wh, acc[mt][j], 0, 0, 0);
      }
    }
  }

  // ---- epilogue: acc -> LDS [64 l][132] fp32 -> packed bf16 uint4 coalesced stores ----
  __syncthreads();  // AB dead
  float* LF = (float*)smem;
#pragma unroll
  for (int j = 0; j < 4; j++) {
    const int gc = wn + j * 16 + nl;
    const float bv = bias[gc];
#pragma unroll
    for (int mt = 0; mt < 2; mt++)
#pragma unroll
      for (int r = 0; r < 4; r++)
        LF[(wm + mt * 16 + q * 4 + r) * LFP + gc] = acc[mt][j][r] + bv;
  }
  __syncthreads();
  // 1024 uint4 chunks: c = h(3b) | l(6b) | half(1b); wave writes contiguous 1 KB per h
#pragma unroll
  for (int i = 0; i < 4; i++) {
    const int c = t + i * 256;
    const int h = c >> 7, rem = c & 127, l = rem >> 1, half = rem & 1;
    const float* sp = LF + l * LFP + h * 16 + half * 8;
    uint4 st;
    st.x = ((unsigned)f2bf_rne(sp[1]) << 16) | f2bf_rne(sp[0]);
    st.y = ((unsigned)f2bf_rne(sp[3]) << 16) | f2bf_rne(sp[2]);
    st.z = ((unsigned)f2bf_rne(sp[5]) << 16) | f2bf_rne(sp[4]);
    st.w = ((unsigned)f2bf_rne(sp[7]) << 16) | f2bf_rne(sp[6]);
    *(uint4*)(value + ((size_t)(b * NHEAD + h) * LTOT + ml0 + l) * DHD + half * 8) = st;
  }
}

// K2: per 32-l tile: stage ext -> qa GEMM (LDS only) -> sampling params ->
// quad-coop gather from bf16 value (XCD-affine b) -> out GEMM, direct f4 stores.
// 256 thr, 40960 B LDS -> 4 blocks/CU; 1024 independent blocks.
__global__ __launch_bounds__(256, 4) void samp(const float* __restrict__ ext,
                                               const unsigned short* __restrict__ value,
                                               const unsigned short* __restrict__ wf_qa,
                                               const unsigned short* __restrict__ wf_out,
                                               const float* __restrict__ bias_qa,
                                               const float* __restrict__ b_out,
                                               float* __restrict__ out) {
  __shared__ char smem[40960];
  unsigned short* AB = (unsigned short*)smem;            // [32][128] hi; lo at +4096 us
  float* qaT = (float*)(smem + 16384);                   // [32][QAP] = 24576 B
  float2* WXY = (float2*)smem;                           // [8][256] = 16384 B
  float* WA = (float*)(smem + 16384);                    // [8][256] = 8192 B
  unsigned short* FR = (unsigned short*)(smem + 24576);  // [32][128] bf16 = 8192 B

  const int t = threadIdx.x;
  const int b = blockIdx.x & 7;                          // XCD affinity
  const int ml0 = (blockIdx.x >> 3) * 32;
  const int w = t >> 6, lane = t & 63;
  const int nl = lane & 15, q = lane >> 4;

  // ---- stage ext 32-l tile (fp32 -> bf16 hi/lo, swizzled) ----
  {
    const float* src = ext + (size_t)b * CM * LTOT + ml0;
    const int x = t & 31, kq = t >> 5;  // kq 0..7
#pragma unroll
    for (int i = 0; i < 4; i++) {
      const int kb = i * 32 + kq * 4;
      ushort4 hi, lo;
      split_bf(src[(size_t)(kb + 0) * LTOT + x], hi.x, lo.x);
      split_bf(src[(size_t)(kb + 1) * LTOT + x], hi.y, lo.y);
      split_bf(src[(size_t)(kb + 2) * LTOT + x], hi.z, lo.z);
      split_bf(src[(size_t)(kb + 3) * LTOT + x], hi.w, lo.w);
      const int off = x * 128 + (((kb >> 3) ^ (x & 15)) << 3) + (kb & 7);
      *(ushort4*)(AB + off) = hi;
      *(ushort4*)(AB + 4096 + off) = lo;
    }
  }
  __syncthreads();

  // ---- qa GEMM: 32m x 192n, 4 waves, wave = 16m x 96n; result -> qaT (LDS) ----
  {
    const int wm = (w & 1) * 16;
    const int wn = (w >> 1) * 96;
    floatx4 acc[6];
#pragma unroll
    for (int j = 0; j < 6; j++) acc[j] = {0.0f, 0.0f, 0.0f, 0.0f};
#pragma unroll
    for (int K0 = 0; K0 < 4; K0++) {
      const int m = wm + nl;
      const int off = m * 128 + (((K0 * 4 + q) ^ (m & 15)) << 3);
      const bf16x8 ah = *(bf16x8*)(AB + off);
      const bf16x8 al = *(bf16x8*)(AB + 4096 + off);
#pragma unroll
      for (int j = 0; j < 6; j++) {
        const size_t o = (size_t)(K0 * 4 + q) * NQA * 8 + (wn + j * 16 + nl) * 8;
        const bf16x8 wh = *(const bf16x8*)(wf_qa + o);
        const bf16x8 wl = *(const bf16x8*)(wf_qa + (size_t)NQA * 128 + o);
        acc[j] = __builtin_amdgcn_mfma_f32_16x16x32_bf16(al, wh, acc[j], 0, 0, 0);
        acc[j] = __builtin_amdgcn_mfma_f32_16x16x32_bf16(ah, wl, acc[j], 0, 0, 0);
        acc[j] = __builtin_amdgcn_mfma_f32_16x16x32_bf16(ah, wh, acc[j], 0, 0, 0);
      }
    }
#pragma unroll
    for (int j = 0; j < 6; j++) {
      const int n = wn + j * 16 + nl;
      const float bv = bias_qa[n];
#pragma unroll
      for (int r = 0; r < 4; r++)
        qaT[(wm + q * 4 + r) * QAP + n] = acc[j][r] + bv;
    }
  }
  __syncthreads();

  // ---- sampling params: thread = (ll = t>>3, h = t&7) ----
  {
    const int ll = t >> 3, h = t & 7;
    const float* qrow = qaT + ll * QAP;
    float4 of[4];
#pragma unroll
    for (int j = 0; j < 4; j++) of[j] = *(const float4*)(qrow + h * 16 + j * 4);
    const float4 lga = *(const float4*)(qrow + 128 + h * 8);
    const float4 lgb = *(const float4*)(qrow + 128 + h * 8 + 4);
    __syncthreads();  // qaT fully read -> WXY/WA may overwrite
    const float lg[8] = {lga.x, lga.y, lga.z, lga.w, lgb.x, lgb.y, lgb.z, lgb.w};
    float m = lg[0];
#pragma unroll
    for (int p = 1; p < 8; p++) m = fmaxf(m, lg[p]);
    float e[8], s = 0.0f;
#pragma unroll
    for (int p = 0; p < 8; p++) { e[p] = __expf(lg[p] - m); s += e[p]; }
    const float inv = 1.0f / s;
    const int l = ml0 + ll;
    const float xf = (float)(l & (WS - 1));
    const float yf = (float)(l >> 6);
#pragma unroll
    for (int p = 0; p < 8; p++) {
      const float ox = (p & 1) ? of[p >> 1].z : of[p >> 1].x;
      const float oy = (p & 1) ? of[p >> 1].w : of[p >> 1].y;
      WXY[p * 256 + t] = {xf + 10.0f * fast_tanh(ox), yf + 10.0f * fast_tanh(oy)};
      WA[p * 256 + t] = e[p] * inv;
    }
  }
  __syncthreads();

  // ---- gather: thread = (uu=(ll,h), d4), 4 passes; bf16 value, quad-coop ----
  {
    const int d4 = t & 3;
    const int u = t >> 2;  // 0..63
#pragma unroll
    for (int ps = 0; ps < 4; ps++) {
      const int uu = ps * 64 + u;
      const int ll = uu >> 3;
      const int h = uu & 7;
      const unsigned short* vbb = value + ((size_t)(b * NHEAD + h) * LTOT) * DHD + d4 * 4;

      float4 o = {0.0f, 0.0f, 0.0f, 0.0f};
#pragma unroll
      for (int p = 0; p < 8; p++) {
        const float2 pxy = WXY[p * 256 + uu];
        const float aw = WA[p * 256 + uu];
        const float x0f = floorf(pxy.x), y0f = floorf(pxy.y);
        const float fx = pxy.x - x0f, fy = pxy.y - y0f;
        const int ix = (int)x0f, iy = (int)y0f;
#pragma unroll
        for (int c = 0; c < 4; c++) {
          const int cdx = c & 1, cdy = c >> 1;
          const int jx = ix + cdx, jy = iy + cdy;
          const float wx = cdx ? fx : 1.0f - fx;
          const float wy = cdy ? fy : 1.0f - fy;
          const bool valid = ((unsigned)jx < WS) & ((unsigned)jy < HS);
          const float wc = valid ? aw * wx * wy : 0.0f;
          const int cx = min(max(jx, 0), WS - 1);
          const int cy = min(max(jy, 0), HS - 1);
          const uint2 rw = *(const uint2*)(vbb + (size_t)((cy << 6) + cx) * DHD);
          o.x += wc * __uint_as_float(rw.x << 16);
          o.y += wc * __uint_as_float(rw.x & 0xFFFF0000u);
          o.z += wc * __uint_as_float(rw.y << 16);
          o.w += wc * __uint_as_float(rw.y & 0xFFFF0000u);
        }
      }
      const int off = ll * 128 + (((h * 2 + (d4 >> 1)) ^ (ll & 15)) << 3) + (d4 & 1) * 4;
      ushort4 st = {f2bf_rne(o.x), f2bf_rne(o.y), f2bf_rne(o.z), f2bf_rne(o.w)};
      *(ushort4*)(FR + off) = st;
    }
  }
  __syncthreads();

  // ---- out GEMM: 32m x 128n, 4 waves, wave = 16m x 64n; direct float4 stores ----
  {
    const int wm = (w & 1) * 16;
    const int wn = (w >> 1) * 64;
    floatx4 acc[4];
#pragma unroll
    for (int j = 0; j < 4; j++) acc[j] = {0.0f, 0.0f, 0.0f, 0.0f};
#pragma unroll
    for (int K0 = 0; K0 < 4; K0++) {
      const int m = wm + nl;
      const int off = m * 128 + (((K0 * 4 + q) ^ (m & 15)) << 3);
      const bf16x8 ah = *(bf16x8*)(FR + off);
#pragma unroll
      for (int j = 0; j < 4; j++) {
        const int n = wn + j * 16 + nl;
        const size_t o = (size_t)(K0 * 4 + q) * CM * 8 + n * 8;
        const bf16x8 wh = *(const bf16x8*)(wf_out + o);
        const bf16x8 wl = *(const bf16x8*)(wf_out + (size_t)CM * 128 + o);
        acc[j] = __builtin_amdgcn_mfma_f32_16x16x32_bf16(ah, wl, acc[j], 0, 0, 0);
        acc[j] = __builtin_amdgcn_mfma_f32_16x16x32_bf16(ah, wh, acc[j], 0, 0, 0);
      }
    }
    // C/D: col=nl -> n, rows q*4+r -> m (contiguous in bchw) => float4 store
#pragma unroll
    for (int j = 0; j < 4; j++) {
      const int gc = wn + j * 16 + nl;
      const float bv = b_out[gc];
      float4 st = {acc[j][0] + bv, acc[j][1] + bv, acc[j][2] + bv, acc[j][3] + bv};
      *(float4*)(out + ((size_t)b * CM + gc) * LTOT + ml0 + wm + q * 4) = st;
    }
  }
}

extern "C" void kernel_launch(void* const* d_in, const int* in_sizes, int n_in,
                              void* d_out, int out_size, void* d_ws, size_t ws_size,
                              hipStream_t stream) {
  const float* nbr    = (const float*)d_in[0];
  const float* ext    = (const float*)d_in[1];
  const float* W_val  = (const float*)d_in[2];
  const float* b_val  = (const float*)d_in[3];
  const float* W_off  = (const float*)d_in[4];
  const float* b_off  = (const float*)d_in[5];
  const float* W_attn = (const float*)d_in[6];
  const float* b_attn = (const float*)d_in[7];
  const float* W_out  = (const float*)d_in[8];
  const float* b_out  = (const float*)d_in[9];
  float* out = (float*)d_out;

  unsigned short* value = (unsigned short*)d_ws;             // 8.39 MB bf16 [b][h][l][16]
  unsigned short* wf_val = value + (size_t)HB * NHEAD * LTOT * DHD;  // 64 KB
  unsigned short* wf_qa  = wf_val + 128 * 128 * 2;           // 96 KB
  unsigned short* wf_out = wf_qa + 192 * 128 * 2;            // 64 KB
  float* bias_qa = (float*)(wf_out + 128 * 128 * 2);         // 768 B

  prep<<<56, 256, 0, stream>>>(W_val, W_off, W_attn, W_out, b_off, b_attn,
                               wf_val, wf_qa, wf_out, bias_qa);
  gemm_val<<<dim3(64, HB), 256, 0, stream>>>(nbr, wf_val, b_val, value);
  samp<<<dim3(128 * HB), 256, 0, stream>>>(ext, value, wf_qa, wf_out, bias_qa, b_out, out);
}